// Round 5
// baseline (403.878 us; speedup 1.0000x reference)
//
#include <hip/hip_runtime.h>

// ---------------------------------------------------------------------------
// MultiChev: 3 ChebConv layers (K=1,2,3) shared graph, concat outputs.
// Round 9: fused single-pass GEMM (all 3 segments per block).
//   r4 state: build fixed (two-level partition); top dispatch is the
//   harness's 480MB ws-poison fill (not ours). gemm was re-reading xb 4x /
//   tx1b 2x across the 3-seg grid (~90MB) + per-seg Ws LDS staging.
//   Fix: one block stages xb/tx1b/tx2 tiles once (24KB LDS, 1 barrier),
//   holds 21 accs, reads W B-fragments straight from global in fragment-
//   native layout (L2-hot, coalesced, no LDS staging). 90MB -> 38MB reads,
//   grid 4689 -> 1563 blocks.
// ---------------------------------------------------------------------------

typedef __attribute__((ext_vector_type(8))) short short8;
typedef __attribute__((ext_vector_type(8))) unsigned short ushort8;
typedef __attribute__((ext_vector_type(4))) float f32x4;

#define NSBMAX 64       // max super-buckets (2048 nodes each) -> N <= 131072
#define NSPLIT 16       // blocks per super-bucket in level-B kernels

__device__ inline float bf2f(unsigned short u) {
    return __uint_as_float(((unsigned int)u) << 16);
}
__device__ inline unsigned short f2bf(float f) {
    unsigned int u = __float_as_uint(f);
    u = (u + 0x7FFF + ((u >> 16) & 1)) >> 16;  // RNE
    return (unsigned short)u;
}

// ---- level A: bin edges into 2048-node super-buckets (col AND row) -------
// colA record: meta = (c&2047)<<17 | r  (r<2^17), w.  rowA record: (r, w).
__global__ __launch_bounds__(512) void partA_kernel(
        const int* __restrict__ row, const int* __restrict__ col,
        const float* __restrict__ ew, int* __restrict__ colAcur,
        int* __restrict__ rowAcur, uint2* __restrict__ colA,
        uint2* __restrict__ rowA, int E, int nsb, int chunk, int capA) {
    __shared__ int hc[NSBMAX];
    __shared__ int hr[NSBMAX];
    const int t = threadIdx.x;
    const int s = blockIdx.x * chunk;
    const int e = min(E, s + chunk);
    if (s >= E) return;
    if (t < NSBMAX) { hc[t] = 0; hr[t] = 0; }
    __syncthreads();
    for (int i = s + t; i < e; i += 512) {
        atomicAdd(&hc[col[i] >> 11], 1);
        atomicAdd(&hr[row[i] >> 11], 1);
    }
    __syncthreads();
    if (t < nsb) {
        int n = hc[t];
        hc[t] = n ? atomicAdd(&colAcur[t], n) : 0;
        n = hr[t];
        hr[t] = n ? atomicAdd(&rowAcur[t], n) : 0;
    }
    __syncthreads();
    for (int i = s + t; i < e; i += 512) {
        int r = row[i], c = col[i];
        float w = ew[i];
        int pc = atomicAdd(&hc[c >> 11], 1);
        if (pc < capA)
            colA[(size_t)(c >> 11) * capA + pc] =
                make_uint2(((unsigned)(c & 2047) << 17) | (unsigned)r, __float_as_uint(w));
        int pr = atomicAdd(&hr[r >> 11], 1);
        if (pr < capA)
            rowA[(size_t)(r >> 11) * capA + pr] = make_uint2((unsigned)r, __float_as_uint(w));
    }
}

// ---- level B: split each col super-bucket into 8 fine 256-node buckets ---
// fine bin f = meta>>25 (3 bits). colB record: meta2 = coff<<24 | r.
__global__ __launch_bounds__(512) void partB_kernel(
        const int* __restrict__ colAcur, const uint2* __restrict__ colA,
        int* __restrict__ colBcur, uint2* __restrict__ colB,
        int capA, int capB) {
    __shared__ int h[8];
    const int sb = blockIdx.x / NSPLIT;
    const int j = blockIdx.x % NSPLIT;
    const int t = threadIdx.x;
    const int cnt = min(colAcur[sb], capA);
    const int chunk = (cnt + NSPLIT - 1) / NSPLIT;
    const int s = j * chunk;
    const int e = min(cnt, s + chunk);
    if (t < 8) h[t] = 0;
    __syncthreads();
    const uint2* part = colA + (size_t)sb * capA;
    for (int i = s + t; i < e; i += 512) atomicAdd(&h[part[i].x >> 25], 1);
    __syncthreads();
    if (t < 8) {
        int n = h[t];
        h[t] = n ? atomicAdd(&colBcur[sb * 8 + t], n) : 0;
    }
    __syncthreads();
    for (int i = s + t; i < e; i += 512) {
        uint2 rec = part[i];
        int f = rec.x >> 25;
        int p = atomicAdd(&h[f], 1);
        if (p < capB) {
            unsigned coff = (rec.x >> 17) & 255u;
            unsigned r = rec.x & 0x1FFFFu;
            colB[(size_t)(sb * 8 + f) * capB + p] = make_uint2((coff << 24) | r, rec.y);
        }
    }
}

// ---- level B rows: per-super partial deg sums in LDS ---------------------
__global__ __launch_bounds__(512) void fine_rowp_kernel(
        const int* __restrict__ rowAcur, const uint2* __restrict__ rowA,
        float* __restrict__ partial, int capA) {
    __shared__ float sdeg[2048];
    const int sb = blockIdx.x / NSPLIT;
    const int j = blockIdx.x % NSPLIT;
    const int t = threadIdx.x;
    const int cnt = min(rowAcur[sb], capA);
    const int chunk = (cnt + NSPLIT - 1) / NSPLIT;
    const int s = j * chunk;
    const int e = min(cnt, s + chunk);
    for (int k = t; k < 2048; k += 512) sdeg[k] = 0.f;
    __syncthreads();
    const uint2* part = rowA + (size_t)sb * capA;
    for (int i = s + t; i < e; i += 512) {
        uint2 rec = part[i];
        atomicAdd(&sdeg[rec.x & 2047u], __uint_as_float(rec.y));
    }
    __syncthreads();
    float* dstp = partial + (size_t)blockIdx.x * 2048;
    for (int k = t; k < 2048; k += 512) dstp[k] = sdeg[k];
}

// ---- exclusive prefix over fine col-bucket sizes -------------------------
__global__ void colbase_scan_kernel(const int* __restrict__ colBcur,
                                    int* __restrict__ colbase,
                                    int* __restrict__ rowptr, int N, int nfb, int capB) {
    __shared__ int s[512];
    int t = threadIdx.x;
    int v = (t < nfb) ? min(colBcur[t], capB) : 0;
    s[t] = v;
    __syncthreads();
    for (int o = 1; o < 512; o <<= 1) {
        int u = (t >= o) ? s[t - o] : 0;
        __syncthreads();
        s[t] += u;
        __syncthreads();
    }
    if (t < nfb) colbase[t] = s[t] - v;
    if (t == 511) rowptr[N] = s[511];
}

// ---- per fine col-bucket CSR build (records grouped by col) --------------
__global__ __launch_bounds__(256) void fine_col_kernel(
        const int* __restrict__ colBcur, const int* __restrict__ colbase,
        const uint2* __restrict__ colB, const float* __restrict__ dis,
        uint2* __restrict__ erec, int* __restrict__ rowptr, int N, int capB) {
    __shared__ int h[256];
    __shared__ int sc[256];
    __shared__ int cur[256];
    const int b = blockIdx.x, t = threadIdx.x;
    const int sz = min(colBcur[b], capB);
    const uint2* part = colB + (size_t)b * capB;
    h[t] = 0;
    __syncthreads();
    for (int i = t; i < sz; i += 256) atomicAdd(&h[part[i].x >> 24], 1);
    __syncthreads();
    int v = h[t];
    sc[t] = v;
    __syncthreads();
    for (int o = 1; o < 256; o <<= 1) {
        int u = (t >= o) ? sc[t - o] : 0;
        __syncthreads();
        sc[t] += u;
        __syncthreads();
    }
    int excl = sc[t] - v;
    const int base = colbase[b];
    int c = (b << 8) + t;
    if (c < N) rowptr[c] = base + excl;
    cur[t] = excl;
    __syncthreads();
    for (int i = t; i < sz; i += 256) {
        uint2 rec = part[i];
        int coff = rec.x >> 24;
        int r = rec.x & 0xFFFFFFu;
        int pos = atomicAdd(&cur[coff], 1);
        float wd = __uint_as_float(rec.y) * dis[r];  // fold dis[row] into record
        erec[(size_t)base + pos] = make_uint2((unsigned)r, __float_as_uint(wd));
    }
}

// ---- fallback path (compact CSR, device-scope atomics) -------------------
__global__ void deg_count_kernel(const int* __restrict__ row, const int* __restrict__ col,
                                 const float* __restrict__ ew,
                                 float* __restrict__ deg, int* __restrict__ cnt, int E) {
    int e = blockIdx.x * 256 + threadIdx.x;
    if (e < E) {
        atomicAdd(&deg[row[e]], ew[e]);
        atomicAdd(&cnt[col[e]], 1);
    }
}

__global__ void scan1_kernel(const int* __restrict__ cnt, int* __restrict__ pre,
                             int* __restrict__ bsum, int N) {
    __shared__ int s[256];
    int t = threadIdx.x;
    int i = blockIdx.x * 256 + t;
    int v = (i < N) ? cnt[i] : 0;
    s[t] = v;
    __syncthreads();
    for (int o = 1; o < 256; o <<= 1) {
        int u = (t >= o) ? s[t - o] : 0;
        __syncthreads();
        s[t] += u;
        __syncthreads();
    }
    if (i < N) pre[i] = s[t] - v;
    if (t == 255) bsum[blockIdx.x] = s[255];
}

__global__ void scan2_kernel(const int* __restrict__ bsum, int* __restrict__ bpre, int nb) {
    __shared__ int s[512];
    int t = threadIdx.x;
    int v = (t < nb) ? bsum[t] : 0;
    s[t] = v;
    __syncthreads();
    for (int o = 1; o < 512; o <<= 1) {
        int u = (t >= o) ? s[t - o] : 0;
        __syncthreads();
        s[t] += u;
        __syncthreads();
    }
    if (t < nb) bpre[t] = s[t] - v;
}

__global__ void scan3_kernel(int* __restrict__ rowptr, int* __restrict__ cursor,
                             const int* __restrict__ bpre, int N, int E) {
    int i = blockIdx.x * 256 + threadIdx.x;
    if (i < N) {
        int v = rowptr[i] + bpre[i >> 8];
        rowptr[i] = v;
        cursor[i] = v;
    }
    if (i == 0) rowptr[N] = E;
}

__global__ void scatter_compact_kernel(const int* __restrict__ row, const int* __restrict__ col,
                                       const float* __restrict__ ew, int* __restrict__ cursor,
                                       uint2* __restrict__ erec, int E) {
    int e = blockIdx.x * 256 + threadIdx.x;
    if (e < E) {
        int p = atomicAdd(&cursor[col[e]], 1);
        erec[p] = make_uint2((unsigned)row[e], __float_as_uint(ew[e]));
    }
}

// ---- x -> bf16; dis from deg (mode 1) or 16-way partials (mode 2) --------
__global__ void cvt_dis_kernel(const float* __restrict__ x, unsigned short* __restrict__ xb,
                               const float* __restrict__ degp, float* __restrict__ dis,
                               int N, int total4, int mode) {
    int i = blockIdx.x * 256 + threadIdx.x;
    if (i < total4) {
        float4 v = reinterpret_cast<const float4*>(x)[i];
        ushort4 o;
        o.x = f2bf(v.x); o.y = f2bf(v.y); o.z = f2bf(v.z); o.w = f2bf(v.w);
        reinterpret_cast<ushort4*>(xb)[i] = o;
    }
    if (mode && i < N) {
        float d;
        if (mode == 2) {
            const float* p = degp + ((size_t)(i >> 11) * NSPLIT) * 2048 + (i & 2047);
            d = 0.f;
#pragma unroll
            for (int j = 0; j < NSPLIT; ++j) d += p[(size_t)j * 2048];
        } else {
            d = degp[i];
        }
        dis[i] = (d > 0.f) ? rsqrtf(d) : 0.f;
    }
}

// ---- gather prop: one wave per dst node, lane = channel ------------------
// premul=1: record.y already holds w*dis[row]; premul=0: multiply dis[row].
__global__ void gather_kernel(const int* __restrict__ ptr, const uint2* __restrict__ erec,
                              const float* __restrict__ dis,
                              const unsigned short* __restrict__ src,
                              unsigned short* __restrict__ dst, int N, int premul) {
    int node = blockIdx.x * 4 + (threadIdx.x >> 6);
    int lane = threadIdx.x & 63;
    if (node >= N) return;
    int s = ptr[node];
    int d = ptr[node + 1] - s;
    float acc = 0.f;
    for (int base = 0; base < d; base += 64) {
        int n = min(64, d - base);
        int ex = 0;
        float w = 0.f;
        if (lane < n) {
            uint2 e = erec[s + base + lane];
            ex = (int)e.x;
            w = __uint_as_float(e.y);
            if (!premul) w *= dis[ex];
        }
        int n4 = (n + 3) & ~3;
        for (int j = 0; j < n4; j += 4) {
            int r0 = __shfl(ex, j + 0, 64);
            int r1 = __shfl(ex, j + 1, 64);
            int r2 = __shfl(ex, j + 2, 64);
            int r3 = __shfl(ex, j + 3, 64);
            float w0 = __shfl(w, j + 0, 64);
            float w1 = __shfl(w, j + 1, 64);
            float w2 = __shfl(w, j + 2, 64);
            float w3 = __shfl(w, j + 3, 64);
            float v0 = bf2f(src[(size_t)r0 * 64 + lane]);
            float v1 = bf2f(src[(size_t)r1 * 64 + lane]);
            float v2 = bf2f(src[(size_t)r2 * 64 + lane]);
            float v3 = bf2f(src[(size_t)r3 * 64 + lane]);
            acc = fmaf(w0, v0, acc);
            acc = fmaf(w1, v1, acc);
            acc = fmaf(w2, v2, acc);
            acc = fmaf(w3, v3, acc);
        }
    }
    dst[(size_t)node * 64 + lane] = f2bf(-dis[node] * acc);
}

// ---- W pre-pack into fragment-native global images -----------------------
// imgW2[img][t(7)][ks(2)][lane(64)][j(8)]: lane l holds B-fragment shorts
// W[ks*32 + (l>>4)*8 + j][t*16 + (l&15)] for mfma_f32_16x16x32_bf16.
__global__ void prep_w_kernel(const float* __restrict__ W10, const float* __restrict__ W20,
                              const float* __restrict__ W21, const float* __restrict__ W30,
                              const float* __restrict__ W31, const float* __restrict__ W32,
                              unsigned short* __restrict__ imgW) {
    int i = blockIdx.x * 256 + threadIdx.x;
    if (i >= 6 * 7168) return;
    int img = i / 7168;
    int rem = i - img * 7168;
    int j = rem & 7;
    int l = (rem >> 3) & 63;
    int ks = (rem >> 9) & 1;
    int t = rem >> 10;            // 0..6
    const float* W;
    switch (img) {
        case 0: W = W10; break;
        case 1: W = W20; break;
        case 2: W = W21; break;
        case 3: W = W30; break;
        case 4: W = W31; break;
        default: W = W32; break;
    }
    int n = t * 16 + (l & 15);
    int k = ks * 32 + (l >> 4) * 8 + j;
    float v = (n < 100) ? W[k * 100 + n] : 0.f;
    imgW[i] = f2bf(v);
}

// ---- fused MFMA gemm: block = 64 rows x ALL 300 output cols --------------
// Stages xb/tx1b/tx2 tiles once; B-fragments read straight from global
// imgW2 (L2-hot, per-lane contiguous 16B). 21 accumulators (3 seg x 7 t).
#define PRODUCT(AF, IMGOFF, SEGBASE)                                                   \
    do {                                                                               \
        _Pragma("unroll") for (int ks = 0; ks < 2; ++ks) {                             \
            _Pragma("unroll") for (int t = 0; t < 7; ++t) {                            \
                short8 bfr = *reinterpret_cast<const short8*>(                         \
                    imgW + (IMGOFF) + ((t * 2 + ks) << 9) + (l << 3));                 \
                acc[(SEGBASE) + t] = __builtin_amdgcn_mfma_f32_16x16x32_bf16(          \
                    AF[ks], bfr, acc[(SEGBASE) + t], 0, 0, 0);                         \
            }                                                                          \
        }                                                                              \
    } while (0)

__global__ __launch_bounds__(256) void gemm_fused_kernel(
        const unsigned short* __restrict__ xb, const unsigned short* __restrict__ tx1b,
        const unsigned short* __restrict__ p2b, const unsigned short* __restrict__ imgW,
        const float* __restrict__ b1, const float* __restrict__ b2,
        const float* __restrict__ b3, float* __restrict__ out, int N) {
    __shared__ unsigned short Ftx[64 * 64];
    __shared__ unsigned short Ft1[64 * 64];
    __shared__ unsigned short Ft2[64 * 64];
    const int row0 = blockIdx.x * 64;
    const int tid = threadIdx.x;
    const int wv = tid >> 6;
    const int l = tid & 63;
    const int m = l & 15;
    const int q = l >> 4;

    f32x4 acc[21];
#pragma unroll
    for (int t = 0; t < 21; ++t) acc[t] = (f32x4){0.f, 0.f, 0.f, 0.f};

    // stage all 3 A-tiles (swizzled LDS layout, conflict-free b128 reads)
#pragma unroll
    for (int it = 0; it < 2; ++it) {
        int i = tid + it * 256;
        int r = i >> 3, g = i & 7;
        int grow = row0 + r;
        ushort8 vx = {0, 0, 0, 0, 0, 0, 0, 0};
        ushort8 v1 = vx, v2 = vx;
        if (grow < N) {
            vx = *reinterpret_cast<const ushort8*>(xb + (size_t)grow * 64 + g * 8);
            v1 = *reinterpret_cast<const ushort8*>(tx1b + (size_t)grow * 64 + g * 8);
            ushort8 vp = *reinterpret_cast<const ushort8*>(p2b + (size_t)grow * 64 + g * 8);
#pragma unroll
            for (int jj = 0; jj < 8; ++jj)
                v2[jj] = f2bf(2.f * bf2f(vp[jj]) - bf2f(vx[jj]));  // tx2 = 2*p2 - x
        }
        int off = r * 64 + ((g ^ (r & 7)) << 3);
        *reinterpret_cast<ushort8*>(&Ftx[off]) = vx;
        *reinterpret_cast<ushort8*>(&Ft1[off]) = v1;
        *reinterpret_cast<ushort8*>(&Ft2[off]) = v2;
    }
    __syncthreads();

    const int arow = wv * 16 + m;
    short8 ax[2], a1[2], a2[2];
#pragma unroll
    for (int ks = 0; ks < 2; ++ks) {
        int o = arow * 64 + (((ks * 4 + q) ^ (arow & 7)) << 3);
        ax[ks] = *reinterpret_cast<const short8*>(&Ftx[o]);
        a1[ks] = *reinterpret_cast<const short8*>(&Ft1[o]);
        a2[ks] = *reinterpret_cast<const short8*>(&Ft2[o]);
    }

    PRODUCT(ax, 0, 0);          // seg0: T0 @ W10
    PRODUCT(ax, 7168, 7);       // seg1: T0 @ W20
    PRODUCT(a1, 14336, 7);      // seg1: T1 @ W21
    PRODUCT(ax, 21504, 14);     // seg2: T0 @ W30
    PRODUCT(a1, 28672, 14);     // seg2: T1 @ W31
    PRODUCT(a2, 35840, 14);     // seg2: T2 @ W32

#pragma unroll
    for (int seg = 0; seg < 3; ++seg) {
        const float* bs = (seg == 0) ? b1 : (seg == 1) ? b2 : b3;
#pragma unroll
        for (int t = 0; t < 7; ++t) {
            int colseg = t * 16 + m;
            if (colseg >= 100) continue;
            float bv = bs[colseg];
#pragma unroll
            for (int i = 0; i < 4; ++i) {
                int grow = row0 + wv * 16 + q * 4 + i;
                if (grow < N)
                    out[(size_t)grow * 300 + seg * 100 + colseg] = acc[seg * 7 + t][i] + bv;
            }
        }
    }
}

extern "C" void kernel_launch(void* const* d_in, const int* in_sizes, int n_in,
                              void* d_out, int out_size, void* d_ws, size_t ws_size,
                              hipStream_t stream) {
    const float* x   = (const float*)d_in[0];
    const int*   ei  = (const int*)d_in[1];
    const float* ew  = (const float*)d_in[2];
    const float* W10 = (const float*)d_in[3];
    const float* b1  = (const float*)d_in[4];
    const float* W20 = (const float*)d_in[5];
    const float* W21 = (const float*)d_in[6];
    const float* b2  = (const float*)d_in[7];
    const float* W30 = (const float*)d_in[8];
    const float* W31 = (const float*)d_in[9];
    const float* W32 = (const float*)d_in[10];
    const float* b3  = (const float*)d_in[11];
    float* out = (float*)d_out;

    const int N = in_sizes[0] / 64;
    const int E = in_sizes[2];
    const int* row = ei;
    const int* col = ei + E;
    const int nb = (N + 255) / 256;
    const int eb = (E + 255) / 256;

    const int NSB = (N + 2047) >> 11;       // super-buckets (2048 nodes)
    const int nfb = NSB * 8;                // fine buckets (256 nodes)

    int total4 = N * 16;
    int pg = (N + 3) / 4;
    int ntile = (N + 63) / 64;

    // capacities with ~25% + constant slack
    long meanA = ((long)E * 2048 + N - 1) / N;
    int capA = (int)(meanA + meanA / 4 + 1024);
    long meanB = ((long)E * 256 + N - 1) / N;
    int capB = (int)(meanB + meanB / 4 + 512);

    char* base = (char*)d_ws;
    size_t off = 0;
    auto alloc = [&](size_t bytes) { size_t o = off; off = (off + bytes + 15) & ~(size_t)15; return o; };

    // ---- fixed allocations (shared by both paths) ----
    float* dis           = (float*)(base + alloc((size_t)4 * N));
    int*   rowptr        = (int*)(base + alloc((size_t)4 * (N + 1)));
    int*   colAcur       = (int*)(base + alloc((size_t)4 * 640));   // 64+64+512 cursors
    int*   rowAcur       = colAcur + 64;
    int*   colBcur       = colAcur + 128;
    int*   colbase       = (int*)(base + alloc((size_t)4 * 512));
    unsigned short* xb   = (unsigned short*)(base + alloc((size_t)128 * N));
    unsigned short* tx1b = (unsigned short*)(base + alloc((size_t)128 * N));
    unsigned short* p2b  = (unsigned short*)(base + alloc((size_t)128 * N));
    unsigned short* imgW = (unsigned short*)(base + alloc((size_t)2 * 6 * 7168));
    uint2* erec          = (uint2*)(base + alloc((size_t)8 * E));
    size_t mainfix = off;
    uint2* colA          = (uint2*)(base + alloc((size_t)8 * NSB * capA));
    uint2* rowA          = (uint2*)(base + alloc((size_t)8 * NSB * capA));
    uint2* colB          = (uint2*)(base + alloc((size_t)8 * nfb * capB));
    float* partial       = (float*)(base + alloc((size_t)4 * NSB * NSPLIT * 2048));
    size_t mainneed = off;

    bool mainok = (N <= 131072) && (NSB <= NSBMAX) && (nfb <= 512) && (mainneed <= ws_size);

    if (mainok) {
        const int PBLK = 512;
        int chunkA = (E + PBLK - 1) / PBLK;

        hipMemsetAsync(colAcur, 0, (size_t)4 * 640, stream);
        partA_kernel<<<PBLK, 512, 0, stream>>>(row, col, ew, colAcur, rowAcur,
                                               colA, rowA, E, NSB, chunkA, capA);
        partB_kernel<<<NSB * NSPLIT, 512, 0, stream>>>(colAcur, colA, colBcur, colB,
                                                       capA, capB);
        fine_rowp_kernel<<<NSB * NSPLIT, 512, 0, stream>>>(rowAcur, rowA, partial, capA);
        cvt_dis_kernel<<<(total4 + 255) / 256, 256, 0, stream>>>(x, xb, partial, dis,
                                                                 N, total4, 2);
        colbase_scan_kernel<<<1, 512, 0, stream>>>(colBcur, colbase, rowptr, N, nfb, capB);
        fine_col_kernel<<<nfb, 256, 0, stream>>>(colBcur, colbase, colB, dis,
                                                 erec, rowptr, N, capB);
        prep_w_kernel<<<(6 * 7168 + 255) / 256, 256, 0, stream>>>(W10, W20, W21, W30, W31, W32, imgW);

        gather_kernel<<<pg, 256, 0, stream>>>(rowptr, erec, dis, xb, tx1b, N, 1);
        gather_kernel<<<pg, 256, 0, stream>>>(rowptr, erec, dis, tx1b, p2b, N, 1);
        gemm_fused_kernel<<<ntile, 256, 0, stream>>>(xb, tx1b, p2b, imgW, b1, b2, b3, out, N);
    } else {
        // ---- compact-CSR fallback (device-scope atomics) ----
        off = mainfix;
        float* deg    = (float*)(base + alloc((size_t)4 * N));
        int*   cursor = (int*)(base + alloc((size_t)4 * N));
        int*   bsum   = (int*)(base + alloc((size_t)4 * nb));
        int*   bpre   = (int*)(base + alloc((size_t)4 * nb));

        hipMemsetAsync(deg, 0, (size_t)4 * N, stream);
        hipMemsetAsync(cursor, 0, (size_t)4 * N, stream);
        deg_count_kernel<<<eb, 256, 0, stream>>>(row, col, ew, deg, cursor, E);
        scan1_kernel<<<nb, 256, 0, stream>>>(cursor, rowptr, bsum, N);
        scan2_kernel<<<1, 512, 0, stream>>>(bsum, bpre, nb);
        scan3_kernel<<<nb, 256, 0, stream>>>(rowptr, cursor, bpre, N, E);
        scatter_compact_kernel<<<eb, 256, 0, stream>>>(row, col, ew, cursor, erec, E);
        cvt_dis_kernel<<<(total4 + 255) / 256, 256, 0, stream>>>(x, xb, deg, dis, N, total4, 1);
        prep_w_kernel<<<(6 * 7168 + 255) / 256, 256, 0, stream>>>(W10, W20, W21, W30, W31, W32, imgW);

        gather_kernel<<<pg, 256, 0, stream>>>(rowptr, erec, dis, xb, tx1b, N, 0);
        gather_kernel<<<pg, 256, 0, stream>>>(rowptr, erec, dis, tx1b, p2b, N, 0);
        gemm_fused_kernel<<<ntile, 256, 0, stream>>>(xb, tx1b, p2b, imgW, b1, b2, b3, out, N);
    }
}

// Round 6
// 390.386 us; speedup vs baseline: 1.0346x; 1.0346x over previous
//
#include <hip/hip_runtime.h>

// ---------------------------------------------------------------------------
// MultiChev: 3 ChebConv layers (K=1,2,3) shared graph, concat outputs.
// Round 10: fused GEMM with operand-swapped MFMA for float4 epilogue.
//   r5 diagnosis: fused gemm was store-issue bound — C/D layout put each
//   lane's 4 acc elems in 4 different ROWS (same col) -> 84 scalar 4B
//   stores/thread = 33.6M store instrs ~= 55us. MfmaUtil 3.9%, BW 22%.
//   Fix: mfma(W_frag, X_frag) instead of mfma(X_frag, W_frag). A/B operand
//   register mappings are identical (l&15 = non-K idx, (l>>4)*8+j = K idx),
//   so the swap transposes D: lane holds 4 CONSECUTIVE out cols for one row
//   -> 21 float4 stores/thread (4x fewer instrs), float4 bias, one row guard.
// ---------------------------------------------------------------------------

typedef __attribute__((ext_vector_type(8))) short short8;
typedef __attribute__((ext_vector_type(8))) unsigned short ushort8;
typedef __attribute__((ext_vector_type(4))) float f32x4;

#define NSBMAX 64       // max super-buckets (2048 nodes each) -> N <= 131072
#define NSPLIT 16       // blocks per super-bucket in level-B kernels

__device__ inline float bf2f(unsigned short u) {
    return __uint_as_float(((unsigned int)u) << 16);
}
__device__ inline unsigned short f2bf(float f) {
    unsigned int u = __float_as_uint(f);
    u = (u + 0x7FFF + ((u >> 16) & 1)) >> 16;  // RNE
    return (unsigned short)u;
}

// ---- level A: bin edges into 2048-node super-buckets (col AND row) -------
// colA record: meta = (c&2047)<<17 | r  (r<2^17), w.  rowA record: (r, w).
__global__ __launch_bounds__(512) void partA_kernel(
        const int* __restrict__ row, const int* __restrict__ col,
        const float* __restrict__ ew, int* __restrict__ colAcur,
        int* __restrict__ rowAcur, uint2* __restrict__ colA,
        uint2* __restrict__ rowA, int E, int nsb, int chunk, int capA) {
    __shared__ int hc[NSBMAX];
    __shared__ int hr[NSBMAX];
    const int t = threadIdx.x;
    const int s = blockIdx.x * chunk;
    const int e = min(E, s + chunk);
    if (s >= E) return;
    if (t < NSBMAX) { hc[t] = 0; hr[t] = 0; }
    __syncthreads();
    for (int i = s + t; i < e; i += 512) {
        atomicAdd(&hc[col[i] >> 11], 1);
        atomicAdd(&hr[row[i] >> 11], 1);
    }
    __syncthreads();
    if (t < nsb) {
        int n = hc[t];
        hc[t] = n ? atomicAdd(&colAcur[t], n) : 0;
        n = hr[t];
        hr[t] = n ? atomicAdd(&rowAcur[t], n) : 0;
    }
    __syncthreads();
    for (int i = s + t; i < e; i += 512) {
        int r = row[i], c = col[i];
        float w = ew[i];
        int pc = atomicAdd(&hc[c >> 11], 1);
        if (pc < capA)
            colA[(size_t)(c >> 11) * capA + pc] =
                make_uint2(((unsigned)(c & 2047) << 17) | (unsigned)r, __float_as_uint(w));
        int pr = atomicAdd(&hr[r >> 11], 1);
        if (pr < capA)
            rowA[(size_t)(r >> 11) * capA + pr] = make_uint2((unsigned)r, __float_as_uint(w));
    }
}

// ---- level B: split each col super-bucket into 8 fine 256-node buckets ---
// fine bin f = meta>>25 (3 bits). colB record: meta2 = coff<<24 | r.
__global__ __launch_bounds__(512) void partB_kernel(
        const int* __restrict__ colAcur, const uint2* __restrict__ colA,
        int* __restrict__ colBcur, uint2* __restrict__ colB,
        int capA, int capB) {
    __shared__ int h[8];
    const int sb = blockIdx.x / NSPLIT;
    const int j = blockIdx.x % NSPLIT;
    const int t = threadIdx.x;
    const int cnt = min(colAcur[sb], capA);
    const int chunk = (cnt + NSPLIT - 1) / NSPLIT;
    const int s = j * chunk;
    const int e = min(cnt, s + chunk);
    if (t < 8) h[t] = 0;
    __syncthreads();
    const uint2* part = colA + (size_t)sb * capA;
    for (int i = s + t; i < e; i += 512) atomicAdd(&h[part[i].x >> 25], 1);
    __syncthreads();
    if (t < 8) {
        int n = h[t];
        h[t] = n ? atomicAdd(&colBcur[sb * 8 + t], n) : 0;
    }
    __syncthreads();
    for (int i = s + t; i < e; i += 512) {
        uint2 rec = part[i];
        int f = rec.x >> 25;
        int p = atomicAdd(&h[f], 1);
        if (p < capB) {
            unsigned coff = (rec.x >> 17) & 255u;
            unsigned r = rec.x & 0x1FFFFu;
            colB[(size_t)(sb * 8 + f) * capB + p] = make_uint2((coff << 24) | r, rec.y);
        }
    }
}

// ---- level B rows: per-super partial deg sums in LDS ---------------------
__global__ __launch_bounds__(512) void fine_rowp_kernel(
        const int* __restrict__ rowAcur, const uint2* __restrict__ rowA,
        float* __restrict__ partial, int capA) {
    __shared__ float sdeg[2048];
    const int sb = blockIdx.x / NSPLIT;
    const int j = blockIdx.x % NSPLIT;
    const int t = threadIdx.x;
    const int cnt = min(rowAcur[sb], capA);
    const int chunk = (cnt + NSPLIT - 1) / NSPLIT;
    const int s = j * chunk;
    const int e = min(cnt, s + chunk);
    for (int k = t; k < 2048; k += 512) sdeg[k] = 0.f;
    __syncthreads();
    const uint2* part = rowA + (size_t)sb * capA;
    for (int i = s + t; i < e; i += 512) {
        uint2 rec = part[i];
        atomicAdd(&sdeg[rec.x & 2047u], __uint_as_float(rec.y));
    }
    __syncthreads();
    float* dstp = partial + (size_t)blockIdx.x * 2048;
    for (int k = t; k < 2048; k += 512) dstp[k] = sdeg[k];
}

// ---- exclusive prefix over fine col-bucket sizes -------------------------
__global__ void colbase_scan_kernel(const int* __restrict__ colBcur,
                                    int* __restrict__ colbase,
                                    int* __restrict__ rowptr, int N, int nfb, int capB) {
    __shared__ int s[512];
    int t = threadIdx.x;
    int v = (t < nfb) ? min(colBcur[t], capB) : 0;
    s[t] = v;
    __syncthreads();
    for (int o = 1; o < 512; o <<= 1) {
        int u = (t >= o) ? s[t - o] : 0;
        __syncthreads();
        s[t] += u;
        __syncthreads();
    }
    if (t < nfb) colbase[t] = s[t] - v;
    if (t == 511) rowptr[N] = s[511];
}

// ---- per fine col-bucket CSR build (records grouped by col) --------------
__global__ __launch_bounds__(256) void fine_col_kernel(
        const int* __restrict__ colBcur, const int* __restrict__ colbase,
        const uint2* __restrict__ colB, const float* __restrict__ dis,
        uint2* __restrict__ erec, int* __restrict__ rowptr, int N, int capB) {
    __shared__ int h[256];
    __shared__ int sc[256];
    __shared__ int cur[256];
    const int b = blockIdx.x, t = threadIdx.x;
    const int sz = min(colBcur[b], capB);
    const uint2* part = colB + (size_t)b * capB;
    h[t] = 0;
    __syncthreads();
    for (int i = t; i < sz; i += 256) atomicAdd(&h[part[i].x >> 24], 1);
    __syncthreads();
    int v = h[t];
    sc[t] = v;
    __syncthreads();
    for (int o = 1; o < 256; o <<= 1) {
        int u = (t >= o) ? sc[t - o] : 0;
        __syncthreads();
        sc[t] += u;
        __syncthreads();
    }
    int excl = sc[t] - v;
    const int base = colbase[b];
    int c = (b << 8) + t;
    if (c < N) rowptr[c] = base + excl;
    cur[t] = excl;
    __syncthreads();
    for (int i = t; i < sz; i += 256) {
        uint2 rec = part[i];
        int coff = rec.x >> 24;
        int r = rec.x & 0xFFFFFFu;
        int pos = atomicAdd(&cur[coff], 1);
        float wd = __uint_as_float(rec.y) * dis[r];  // fold dis[row] into record
        erec[(size_t)base + pos] = make_uint2((unsigned)r, __float_as_uint(wd));
    }
}

// ---- fallback path (compact CSR, device-scope atomics) -------------------
__global__ void deg_count_kernel(const int* __restrict__ row, const int* __restrict__ col,
                                 const float* __restrict__ ew,
                                 float* __restrict__ deg, int* __restrict__ cnt, int E) {
    int e = blockIdx.x * 256 + threadIdx.x;
    if (e < E) {
        atomicAdd(&deg[row[e]], ew[e]);
        atomicAdd(&cnt[col[e]], 1);
    }
}

__global__ void scan1_kernel(const int* __restrict__ cnt, int* __restrict__ pre,
                             int* __restrict__ bsum, int N) {
    __shared__ int s[256];
    int t = threadIdx.x;
    int i = blockIdx.x * 256 + t;
    int v = (i < N) ? cnt[i] : 0;
    s[t] = v;
    __syncthreads();
    for (int o = 1; o < 256; o <<= 1) {
        int u = (t >= o) ? s[t - o] : 0;
        __syncthreads();
        s[t] += u;
        __syncthreads();
    }
    if (i < N) pre[i] = s[t] - v;
    if (t == 255) bsum[blockIdx.x] = s[255];
}

__global__ void scan2_kernel(const int* __restrict__ bsum, int* __restrict__ bpre, int nb) {
    __shared__ int s[512];
    int t = threadIdx.x;
    int v = (t < nb) ? bsum[t] : 0;
    s[t] = v;
    __syncthreads();
    for (int o = 1; o < 512; o <<= 1) {
        int u = (t >= o) ? s[t - o] : 0;
        __syncthreads();
        s[t] += u;
        __syncthreads();
    }
    if (t < nb) bpre[t] = s[t] - v;
}

__global__ void scan3_kernel(int* __restrict__ rowptr, int* __restrict__ cursor,
                             const int* __restrict__ bpre, int N, int E) {
    int i = blockIdx.x * 256 + threadIdx.x;
    if (i < N) {
        int v = rowptr[i] + bpre[i >> 8];
        rowptr[i] = v;
        cursor[i] = v;
    }
    if (i == 0) rowptr[N] = E;
}

__global__ void scatter_compact_kernel(const int* __restrict__ row, const int* __restrict__ col,
                                       const float* __restrict__ ew, int* __restrict__ cursor,
                                       uint2* __restrict__ erec, int E) {
    int e = blockIdx.x * 256 + threadIdx.x;
    if (e < E) {
        int p = atomicAdd(&cursor[col[e]], 1);
        erec[p] = make_uint2((unsigned)row[e], __float_as_uint(ew[e]));
    }
}

// ---- x -> bf16; dis from deg (mode 1) or 16-way partials (mode 2) --------
__global__ void cvt_dis_kernel(const float* __restrict__ x, unsigned short* __restrict__ xb,
                               const float* __restrict__ degp, float* __restrict__ dis,
                               int N, int total4, int mode) {
    int i = blockIdx.x * 256 + threadIdx.x;
    if (i < total4) {
        float4 v = reinterpret_cast<const float4*>(x)[i];
        ushort4 o;
        o.x = f2bf(v.x); o.y = f2bf(v.y); o.z = f2bf(v.z); o.w = f2bf(v.w);
        reinterpret_cast<ushort4*>(xb)[i] = o;
    }
    if (mode && i < N) {
        float d;
        if (mode == 2) {
            const float* p = degp + ((size_t)(i >> 11) * NSPLIT) * 2048 + (i & 2047);
            d = 0.f;
#pragma unroll
            for (int j = 0; j < NSPLIT; ++j) d += p[(size_t)j * 2048];
        } else {
            d = degp[i];
        }
        dis[i] = (d > 0.f) ? rsqrtf(d) : 0.f;
    }
}

// ---- gather prop: one wave per dst node, lane = channel ------------------
// premul=1: record.y already holds w*dis[row]; premul=0: multiply dis[row].
__global__ void gather_kernel(const int* __restrict__ ptr, const uint2* __restrict__ erec,
                              const float* __restrict__ dis,
                              const unsigned short* __restrict__ src,
                              unsigned short* __restrict__ dst, int N, int premul) {
    int node = blockIdx.x * 4 + (threadIdx.x >> 6);
    int lane = threadIdx.x & 63;
    if (node >= N) return;
    int s = ptr[node];
    int d = ptr[node + 1] - s;
    float acc = 0.f;
    for (int base = 0; base < d; base += 64) {
        int n = min(64, d - base);
        int ex = 0;
        float w = 0.f;
        if (lane < n) {
            uint2 e = erec[s + base + lane];
            ex = (int)e.x;
            w = __uint_as_float(e.y);
            if (!premul) w *= dis[ex];
        }
        int n4 = (n + 3) & ~3;
        for (int j = 0; j < n4; j += 4) {
            int r0 = __shfl(ex, j + 0, 64);
            int r1 = __shfl(ex, j + 1, 64);
            int r2 = __shfl(ex, j + 2, 64);
            int r3 = __shfl(ex, j + 3, 64);
            float w0 = __shfl(w, j + 0, 64);
            float w1 = __shfl(w, j + 1, 64);
            float w2 = __shfl(w, j + 2, 64);
            float w3 = __shfl(w, j + 3, 64);
            float v0 = bf2f(src[(size_t)r0 * 64 + lane]);
            float v1 = bf2f(src[(size_t)r1 * 64 + lane]);
            float v2 = bf2f(src[(size_t)r2 * 64 + lane]);
            float v3 = bf2f(src[(size_t)r3 * 64 + lane]);
            acc = fmaf(w0, v0, acc);
            acc = fmaf(w1, v1, acc);
            acc = fmaf(w2, v2, acc);
            acc = fmaf(w3, v3, acc);
        }
    }
    dst[(size_t)node * 64 + lane] = f2bf(-dis[node] * acc);
}

// ---- W pre-pack into fragment-native global images -----------------------
// imgW2[img][t(7)][ks(2)][lane(64)][j(8)]: lane l holds fragment shorts
// W[ks*32 + (l>>4)*8 + j][t*16 + (l&15)] for mfma_f32_16x16x32_bf16.
__global__ void prep_w_kernel(const float* __restrict__ W10, const float* __restrict__ W20,
                              const float* __restrict__ W21, const float* __restrict__ W30,
                              const float* __restrict__ W31, const float* __restrict__ W32,
                              unsigned short* __restrict__ imgW) {
    int i = blockIdx.x * 256 + threadIdx.x;
    if (i >= 6 * 7168) return;
    int img = i / 7168;
    int rem = i - img * 7168;
    int j = rem & 7;
    int l = (rem >> 3) & 63;
    int ks = (rem >> 9) & 1;
    int t = rem >> 10;            // 0..6
    const float* W;
    switch (img) {
        case 0: W = W10; break;
        case 1: W = W20; break;
        case 2: W = W21; break;
        case 3: W = W30; break;
        case 4: W = W31; break;
        default: W = W32; break;
    }
    int n = t * 16 + (l & 15);
    int k = ks * 32 + (l >> 4) * 8 + j;
    float v = (n < 100) ? W[k * 100 + n] : 0.f;
    imgW[i] = f2bf(v);
}

// ---- fused MFMA gemm: block = 64 rows x ALL 300 output cols --------------
// Operand-swapped MFMA: mfma(W_frag, X_frag) computes (X.W)^T so each lane
// holds 4 CONSECUTIVE output cols of one row -> float4 epilogue stores.
// A/B operand register mappings are identical (l&15 = non-K index,
// (l>>4)*8+j = K index), so the same fragments feed either slot.
#define PRODUCT(AF, IMGOFF, SEGBASE)                                                   \
    do {                                                                               \
        _Pragma("unroll") for (int ks = 0; ks < 2; ++ks) {                             \
            _Pragma("unroll") for (int t = 0; t < 7; ++t) {                            \
                short8 bfr = *reinterpret_cast<const short8*>(                         \
                    imgW + (IMGOFF) + ((t * 2 + ks) << 9) + (l << 3));                 \
                acc[(SEGBASE) + t] = __builtin_amdgcn_mfma_f32_16x16x32_bf16(          \
                    bfr, AF[ks], acc[(SEGBASE) + t], 0, 0, 0);                         \
            }                                                                          \
        }                                                                              \
    } while (0)

__global__ __launch_bounds__(256) void gemm_fused_kernel(
        const unsigned short* __restrict__ xb, const unsigned short* __restrict__ tx1b,
        const unsigned short* __restrict__ p2b, const unsigned short* __restrict__ imgW,
        const float* __restrict__ b1, const float* __restrict__ b2,
        const float* __restrict__ b3, float* __restrict__ out, int N) {
    __shared__ unsigned short Ftx[64 * 64];
    __shared__ unsigned short Ft1[64 * 64];
    __shared__ unsigned short Ft2[64 * 64];
    const int row0 = blockIdx.x * 64;
    const int tid = threadIdx.x;
    const int wv = tid >> 6;
    const int l = tid & 63;
    const int m = l & 15;
    const int q = l >> 4;

    f32x4 acc[21];
#pragma unroll
    for (int t = 0; t < 21; ++t) acc[t] = (f32x4){0.f, 0.f, 0.f, 0.f};

    // stage all 3 A-tiles (swizzled LDS layout, conflict-free b128 reads)
#pragma unroll
    for (int it = 0; it < 2; ++it) {
        int i = tid + it * 256;
        int r = i >> 3, g = i & 7;
        int grow = row0 + r;
        ushort8 vx = {0, 0, 0, 0, 0, 0, 0, 0};
        ushort8 v1 = vx, v2 = vx;
        if (grow < N) {
            vx = *reinterpret_cast<const ushort8*>(xb + (size_t)grow * 64 + g * 8);
            v1 = *reinterpret_cast<const ushort8*>(tx1b + (size_t)grow * 64 + g * 8);
            ushort8 vp = *reinterpret_cast<const ushort8*>(p2b + (size_t)grow * 64 + g * 8);
#pragma unroll
            for (int jj = 0; jj < 8; ++jj)
                v2[jj] = f2bf(2.f * bf2f(vp[jj]) - bf2f(vx[jj]));  // tx2 = 2*p2 - x
        }
        int off = r * 64 + ((g ^ (r & 7)) << 3);
        *reinterpret_cast<ushort8*>(&Ftx[off]) = vx;
        *reinterpret_cast<ushort8*>(&Ft1[off]) = v1;
        *reinterpret_cast<ushort8*>(&Ft2[off]) = v2;
    }
    __syncthreads();

    const int arow = wv * 16 + m;
    short8 ax[2], a1[2], a2[2];
#pragma unroll
    for (int ks = 0; ks < 2; ++ks) {
        int o = arow * 64 + (((ks * 4 + q) ^ (arow & 7)) << 3);
        ax[ks] = *reinterpret_cast<const short8*>(&Ftx[o]);
        a1[ks] = *reinterpret_cast<const short8*>(&Ft1[o]);
        a2[ks] = *reinterpret_cast<const short8*>(&Ft2[o]);
    }

    PRODUCT(ax, 0, 0);          // seg0: T0 @ W10
    PRODUCT(ax, 7168, 7);       // seg1: T0 @ W20
    PRODUCT(a1, 14336, 7);      // seg1: T1 @ W21
    PRODUCT(ax, 21504, 14);     // seg2: T0 @ W30
    PRODUCT(a1, 28672, 14);     // seg2: T1 @ W31
    PRODUCT(a2, 35840, 14);     // seg2: T2 @ W32

    // epilogue: lane (wv,m) owns out row row0+wv*16+m; acc[seg*7+t][i] is
    // col seg*100 + t*16 + q*4 + i  -> contiguous float4 stores.
    const int grow = row0 + wv * 16 + m;
    if (grow < N) {
        float* orow = out + (size_t)grow * 300;
#pragma unroll
        for (int seg = 0; seg < 3; ++seg) {
            const float* bs = (seg == 0) ? b1 : (seg == 1) ? b2 : b3;
#pragma unroll
            for (int t = 0; t < 7; ++t) {
                int c0 = t * 16 + q * 4;
                if (c0 + 3 >= 100) continue;   // t=6: only q==0 (cols 96..99)
                float4 bv = *reinterpret_cast<const float4*>(bs + c0);
                f32x4 a = acc[seg * 7 + t];
                float4 o = make_float4(a[0] + bv.x, a[1] + bv.y, a[2] + bv.z, a[3] + bv.w);
                *reinterpret_cast<float4*>(orow + seg * 100 + c0) = o;
            }
        }
    }
}

extern "C" void kernel_launch(void* const* d_in, const int* in_sizes, int n_in,
                              void* d_out, int out_size, void* d_ws, size_t ws_size,
                              hipStream_t stream) {
    const float* x   = (const float*)d_in[0];
    const int*   ei  = (const int*)d_in[1];
    const float* ew  = (const float*)d_in[2];
    const float* W10 = (const float*)d_in[3];
    const float* b1  = (const float*)d_in[4];
    const float* W20 = (const float*)d_in[5];
    const float* W21 = (const float*)d_in[6];
    const float* b2  = (const float*)d_in[7];
    const float* W30 = (const float*)d_in[8];
    const float* W31 = (const float*)d_in[9];
    const float* W32 = (const float*)d_in[10];
    const float* b3  = (const float*)d_in[11];
    float* out = (float*)d_out;

    const int N = in_sizes[0] / 64;
    const int E = in_sizes[2];
    const int* row = ei;
    const int* col = ei + E;
    const int nb = (N + 255) / 256;
    const int eb = (E + 255) / 256;

    const int NSB = (N + 2047) >> 11;       // super-buckets (2048 nodes)
    const int nfb = NSB * 8;                // fine buckets (256 nodes)

    int total4 = N * 16;
    int pg = (N + 3) / 4;
    int ntile = (N + 63) / 64;

    // capacities with ~25% + constant slack
    long meanA = ((long)E * 2048 + N - 1) / N;
    int capA = (int)(meanA + meanA / 4 + 1024);
    long meanB = ((long)E * 256 + N - 1) / N;
    int capB = (int)(meanB + meanB / 4 + 512);

    char* base = (char*)d_ws;
    size_t off = 0;
    auto alloc = [&](size_t bytes) { size_t o = off; off = (off + bytes + 15) & ~(size_t)15; return o; };

    // ---- fixed allocations (shared by both paths) ----
    float* dis           = (float*)(base + alloc((size_t)4 * N));
    int*   rowptr        = (int*)(base + alloc((size_t)4 * (N + 1)));
    int*   colAcur       = (int*)(base + alloc((size_t)4 * 640));   // 64+64+512 cursors
    int*   rowAcur       = colAcur + 64;
    int*   colBcur       = colAcur + 128;
    int*   colbase       = (int*)(base + alloc((size_t)4 * 512));
    unsigned short* xb   = (unsigned short*)(base + alloc((size_t)128 * N));
    unsigned short* tx1b = (unsigned short*)(base + alloc((size_t)128 * N));
    unsigned short* p2b  = (unsigned short*)(base + alloc((size_t)128 * N));
    unsigned short* imgW = (unsigned short*)(base + alloc((size_t)2 * 6 * 7168));
    uint2* erec          = (uint2*)(base + alloc((size_t)8 * E));
    size_t mainfix = off;
    uint2* colA          = (uint2*)(base + alloc((size_t)8 * NSB * capA));
    uint2* rowA          = (uint2*)(base + alloc((size_t)8 * NSB * capA));
    uint2* colB          = (uint2*)(base + alloc((size_t)8 * nfb * capB));
    float* partial       = (float*)(base + alloc((size_t)4 * NSB * NSPLIT * 2048));
    size_t mainneed = off;

    bool mainok = (N <= 131072) && (NSB <= NSBMAX) && (nfb <= 512) && (mainneed <= ws_size);

    if (mainok) {
        const int PBLK = 512;
        int chunkA = (E + PBLK - 1) / PBLK;

        hipMemsetAsync(colAcur, 0, (size_t)4 * 640, stream);
        partA_kernel<<<PBLK, 512, 0, stream>>>(row, col, ew, colAcur, rowAcur,
                                               colA, rowA, E, NSB, chunkA, capA);
        partB_kernel<<<NSB * NSPLIT, 512, 0, stream>>>(colAcur, colA, colBcur, colB,
                                                       capA, capB);
        fine_rowp_kernel<<<NSB * NSPLIT, 512, 0, stream>>>(rowAcur, rowA, partial, capA);
        cvt_dis_kernel<<<(total4 + 255) / 256, 256, 0, stream>>>(x, xb, partial, dis,
                                                                 N, total4, 2);
        colbase_scan_kernel<<<1, 512, 0, stream>>>(colBcur, colbase, rowptr, N, nfb, capB);
        fine_col_kernel<<<nfb, 256, 0, stream>>>(colBcur, colbase, colB, dis,
                                                 erec, rowptr, N, capB);
        prep_w_kernel<<<(6 * 7168 + 255) / 256, 256, 0, stream>>>(W10, W20, W21, W30, W31, W32, imgW);

        gather_kernel<<<pg, 256, 0, stream>>>(rowptr, erec, dis, xb, tx1b, N, 1);
        gather_kernel<<<pg, 256, 0, stream>>>(rowptr, erec, dis, tx1b, p2b, N, 1);
        gemm_fused_kernel<<<ntile, 256, 0, stream>>>(xb, tx1b, p2b, imgW, b1, b2, b3, out, N);
    } else {
        // ---- compact-CSR fallback (device-scope atomics) ----
        off = mainfix;
        float* deg    = (float*)(base + alloc((size_t)4 * N));
        int*   cursor = (int*)(base + alloc((size_t)4 * N));
        int*   bsum   = (int*)(base + alloc((size_t)4 * nb));
        int*   bpre   = (int*)(base + alloc((size_t)4 * nb));

        hipMemsetAsync(deg, 0, (size_t)4 * N, stream);
        hipMemsetAsync(cursor, 0, (size_t)4 * N, stream);
        deg_count_kernel<<<eb, 256, 0, stream>>>(row, col, ew, deg, cursor, E);
        scan1_kernel<<<nb, 256, 0, stream>>>(cursor, rowptr, bsum, N);
        scan2_kernel<<<1, 512, 0, stream>>>(bsum, bpre, nb);
        scan3_kernel<<<nb, 256, 0, stream>>>(rowptr, cursor, bpre, N, E);
        scatter_compact_kernel<<<eb, 256, 0, stream>>>(row, col, ew, cursor, erec, E);
        cvt_dis_kernel<<<(total4 + 255) / 256, 256, 0, stream>>>(x, xb, deg, dis, N, total4, 1);
        prep_w_kernel<<<(6 * 7168 + 255) / 256, 256, 0, stream>>>(W10, W20, W21, W30, W31, W32, imgW);

        gather_kernel<<<pg, 256, 0, stream>>>(rowptr, erec, dis, xb, tx1b, N, 0);
        gather_kernel<<<pg, 256, 0, stream>>>(rowptr, erec, dis, tx1b, p2b, N, 0);
        gemm_fused_kernel<<<ntile, 256, 0, stream>>>(xb, tx1b, p2b, imgW, b1, b2, b3, out, N);
    }
}

// Round 7
// 388.513 us; speedup vs baseline: 1.0396x; 1.0048x over previous
//
#include <hip/hip_runtime.h>

// ---------------------------------------------------------------------------
// MultiChev: 3 ChebConv layers (K=1,2,3) shared graph, concat outputs.
// Round 11: gather channel-pairing (half VMEM issue), partA occupancy 2x,
//           fine_rowp partial depth 16->8.
//   r6 state: build + fused/swapped gemm all < 78us; top-5 = harness fill.
//   Gathers are the largest block (~E x 128B random L3 lines per pass).
//   Pairing: lane handles 2 channels via one uint load; half-waves take
//   even/odd edges -> 4 loads per 8 edges (was 8), same line traffic.
// ---------------------------------------------------------------------------

typedef __attribute__((ext_vector_type(8))) short short8;
typedef __attribute__((ext_vector_type(8))) unsigned short ushort8;
typedef __attribute__((ext_vector_type(4))) float f32x4;

#define NSBMAX 64       // max super-buckets (2048 nodes each) -> N <= 131072
#define NSPLIT 16       // blocks per super-bucket in partB
#define NSPLIT_ROW 8    // blocks per super-bucket in fine_rowp

__device__ inline float bf2f(unsigned short u) {
    return __uint_as_float(((unsigned int)u) << 16);
}
__device__ inline unsigned short f2bf(float f) {
    unsigned int u = __float_as_uint(f);
    u = (u + 0x7FFF + ((u >> 16) & 1)) >> 16;  // RNE
    return (unsigned short)u;
}

// ---- level A: bin edges into 2048-node super-buckets (col AND row) -------
// colA record: meta = (c&2047)<<17 | r  (r<2^17), w.  rowA record: (r, w).
__global__ __launch_bounds__(512) void partA_kernel(
        const int* __restrict__ row, const int* __restrict__ col,
        const float* __restrict__ ew, int* __restrict__ colAcur,
        int* __restrict__ rowAcur, uint2* __restrict__ colA,
        uint2* __restrict__ rowA, int E, int nsb, int chunk, int capA) {
    __shared__ int hc[NSBMAX];
    __shared__ int hr[NSBMAX];
    const int t = threadIdx.x;
    const int s = blockIdx.x * chunk;
    const int e = min(E, s + chunk);
    if (s >= E) return;
    if (t < NSBMAX) { hc[t] = 0; hr[t] = 0; }
    __syncthreads();
    for (int i = s + t; i < e; i += 512) {
        atomicAdd(&hc[col[i] >> 11], 1);
        atomicAdd(&hr[row[i] >> 11], 1);
    }
    __syncthreads();
    if (t < nsb) {
        int n = hc[t];
        hc[t] = n ? atomicAdd(&colAcur[t], n) : 0;
        n = hr[t];
        hr[t] = n ? atomicAdd(&rowAcur[t], n) : 0;
    }
    __syncthreads();
    for (int i = s + t; i < e; i += 512) {
        int r = row[i], c = col[i];
        float w = ew[i];
        int pc = atomicAdd(&hc[c >> 11], 1);
        if (pc < capA)
            colA[(size_t)(c >> 11) * capA + pc] =
                make_uint2(((unsigned)(c & 2047) << 17) | (unsigned)r, __float_as_uint(w));
        int pr = atomicAdd(&hr[r >> 11], 1);
        if (pr < capA)
            rowA[(size_t)(r >> 11) * capA + pr] = make_uint2((unsigned)r, __float_as_uint(w));
    }
}

// ---- level B: split each col super-bucket into 8 fine 256-node buckets ---
// fine bin f = meta>>25 (3 bits). colB record: meta2 = coff<<24 | r.
__global__ __launch_bounds__(512) void partB_kernel(
        const int* __restrict__ colAcur, const uint2* __restrict__ colA,
        int* __restrict__ colBcur, uint2* __restrict__ colB,
        int capA, int capB) {
    __shared__ int h[8];
    const int sb = blockIdx.x / NSPLIT;
    const int j = blockIdx.x % NSPLIT;
    const int t = threadIdx.x;
    const int cnt = min(colAcur[sb], capA);
    const int chunk = (cnt + NSPLIT - 1) / NSPLIT;
    const int s = j * chunk;
    const int e = min(cnt, s + chunk);
    if (t < 8) h[t] = 0;
    __syncthreads();
    const uint2* part = colA + (size_t)sb * capA;
    for (int i = s + t; i < e; i += 512) atomicAdd(&h[part[i].x >> 25], 1);
    __syncthreads();
    if (t < 8) {
        int n = h[t];
        h[t] = n ? atomicAdd(&colBcur[sb * 8 + t], n) : 0;
    }
    __syncthreads();
    for (int i = s + t; i < e; i += 512) {
        uint2 rec = part[i];
        int f = rec.x >> 25;
        int p = atomicAdd(&h[f], 1);
        if (p < capB) {
            unsigned coff = (rec.x >> 17) & 255u;
            unsigned r = rec.x & 0x1FFFFu;
            colB[(size_t)(sb * 8 + f) * capB + p] = make_uint2((coff << 24) | r, rec.y);
        }
    }
}

// ---- level B rows: per-super partial deg sums in LDS ---------------------
__global__ __launch_bounds__(512) void fine_rowp_kernel(
        const int* __restrict__ rowAcur, const uint2* __restrict__ rowA,
        float* __restrict__ partial, int capA) {
    __shared__ float sdeg[2048];
    const int sb = blockIdx.x / NSPLIT_ROW;
    const int j = blockIdx.x % NSPLIT_ROW;
    const int t = threadIdx.x;
    const int cnt = min(rowAcur[sb], capA);
    const int chunk = (cnt + NSPLIT_ROW - 1) / NSPLIT_ROW;
    const int s = j * chunk;
    const int e = min(cnt, s + chunk);
    for (int k = t; k < 2048; k += 512) sdeg[k] = 0.f;
    __syncthreads();
    const uint2* part = rowA + (size_t)sb * capA;
    for (int i = s + t; i < e; i += 512) {
        uint2 rec = part[i];
        atomicAdd(&sdeg[rec.x & 2047u], __uint_as_float(rec.y));
    }
    __syncthreads();
    float* dstp = partial + (size_t)blockIdx.x * 2048;
    for (int k = t; k < 2048; k += 512) dstp[k] = sdeg[k];
}

// ---- exclusive prefix over fine col-bucket sizes -------------------------
__global__ void colbase_scan_kernel(const int* __restrict__ colBcur,
                                    int* __restrict__ colbase,
                                    int* __restrict__ rowptr, int N, int nfb, int capB) {
    __shared__ int s[512];
    int t = threadIdx.x;
    int v = (t < nfb) ? min(colBcur[t], capB) : 0;
    s[t] = v;
    __syncthreads();
    for (int o = 1; o < 512; o <<= 1) {
        int u = (t >= o) ? s[t - o] : 0;
        __syncthreads();
        s[t] += u;
        __syncthreads();
    }
    if (t < nfb) colbase[t] = s[t] - v;
    if (t == 511) rowptr[N] = s[511];
}

// ---- per fine col-bucket CSR build (records grouped by col) --------------
__global__ __launch_bounds__(256) void fine_col_kernel(
        const int* __restrict__ colBcur, const int* __restrict__ colbase,
        const uint2* __restrict__ colB, const float* __restrict__ dis,
        uint2* __restrict__ erec, int* __restrict__ rowptr, int N, int capB) {
    __shared__ int h[256];
    __shared__ int sc[256];
    __shared__ int cur[256];
    const int b = blockIdx.x, t = threadIdx.x;
    const int sz = min(colBcur[b], capB);
    const uint2* part = colB + (size_t)b * capB;
    h[t] = 0;
    __syncthreads();
    for (int i = t; i < sz; i += 256) atomicAdd(&h[part[i].x >> 24], 1);
    __syncthreads();
    int v = h[t];
    sc[t] = v;
    __syncthreads();
    for (int o = 1; o < 256; o <<= 1) {
        int u = (t >= o) ? sc[t - o] : 0;
        __syncthreads();
        sc[t] += u;
        __syncthreads();
    }
    int excl = sc[t] - v;
    const int base = colbase[b];
    int c = (b << 8) + t;
    if (c < N) rowptr[c] = base + excl;
    cur[t] = excl;
    __syncthreads();
    for (int i = t; i < sz; i += 256) {
        uint2 rec = part[i];
        int coff = rec.x >> 24;
        int r = rec.x & 0xFFFFFFu;
        int pos = atomicAdd(&cur[coff], 1);
        float wd = __uint_as_float(rec.y) * dis[r];  // fold dis[row] into record
        erec[(size_t)base + pos] = make_uint2((unsigned)r, __float_as_uint(wd));
    }
}

// ---- fallback path (compact CSR, device-scope atomics) -------------------
__global__ void deg_count_kernel(const int* __restrict__ row, const int* __restrict__ col,
                                 const float* __restrict__ ew,
                                 float* __restrict__ deg, int* __restrict__ cnt, int E) {
    int e = blockIdx.x * 256 + threadIdx.x;
    if (e < E) {
        atomicAdd(&deg[row[e]], ew[e]);
        atomicAdd(&cnt[col[e]], 1);
    }
}

__global__ void scan1_kernel(const int* __restrict__ cnt, int* __restrict__ pre,
                             int* __restrict__ bsum, int N) {
    __shared__ int s[256];
    int t = threadIdx.x;
    int i = blockIdx.x * 256 + t;
    int v = (i < N) ? cnt[i] : 0;
    s[t] = v;
    __syncthreads();
    for (int o = 1; o < 256; o <<= 1) {
        int u = (t >= o) ? s[t - o] : 0;
        __syncthreads();
        s[t] += u;
        __syncthreads();
    }
    if (i < N) pre[i] = s[t] - v;
    if (t == 255) bsum[blockIdx.x] = s[255];
}

__global__ void scan2_kernel(const int* __restrict__ bsum, int* __restrict__ bpre, int nb) {
    __shared__ int s[512];
    int t = threadIdx.x;
    int v = (t < nb) ? bsum[t] : 0;
    s[t] = v;
    __syncthreads();
    for (int o = 1; o < 512; o <<= 1) {
        int u = (t >= o) ? s[t - o] : 0;
        __syncthreads();
        s[t] += u;
        __syncthreads();
    }
    if (t < nb) bpre[t] = s[t] - v;
}

__global__ void scan3_kernel(int* __restrict__ rowptr, int* __restrict__ cursor,
                             const int* __restrict__ bpre, int N, int E) {
    int i = blockIdx.x * 256 + threadIdx.x;
    if (i < N) {
        int v = rowptr[i] + bpre[i >> 8];
        rowptr[i] = v;
        cursor[i] = v;
    }
    if (i == 0) rowptr[N] = E;
}

__global__ void scatter_compact_kernel(const int* __restrict__ row, const int* __restrict__ col,
                                       const float* __restrict__ ew, int* __restrict__ cursor,
                                       uint2* __restrict__ erec, int E) {
    int e = blockIdx.x * 256 + threadIdx.x;
    if (e < E) {
        int p = atomicAdd(&cursor[col[e]], 1);
        erec[p] = make_uint2((unsigned)row[e], __float_as_uint(ew[e]));
    }
}

// ---- x -> bf16; dis from deg (mode 1) or 8-way partials (mode 2) ---------
__global__ void cvt_dis_kernel(const float* __restrict__ x, unsigned short* __restrict__ xb,
                               const float* __restrict__ degp, float* __restrict__ dis,
                               int N, int total4, int mode) {
    int i = blockIdx.x * 256 + threadIdx.x;
    if (i < total4) {
        float4 v = reinterpret_cast<const float4*>(x)[i];
        ushort4 o;
        o.x = f2bf(v.x); o.y = f2bf(v.y); o.z = f2bf(v.z); o.w = f2bf(v.w);
        reinterpret_cast<ushort4*>(xb)[i] = o;
    }
    if (mode && i < N) {
        float d;
        if (mode == 2) {
            const float* p = degp + ((size_t)(i >> 11) * NSPLIT_ROW) * 2048 + (i & 2047);
            d = 0.f;
#pragma unroll
            for (int j = 0; j < NSPLIT_ROW; ++j) d += p[(size_t)j * 2048];
        } else {
            d = degp[i];
        }
        dis[i] = (d > 0.f) ? rsqrtf(d) : 0.f;
    }
}

// ---- gather prop: one wave per dst node, channel-paired ------------------
// Lane l handles channels (2*(l&31), 2*(l&31)+1) via one uint (ushort2)
// load; half-wave h = l>>5 takes edges of parity h. 4 VMEM loads per 8
// edges (was 8). Partial accs combined by shfl_xor(32); packed 4B stores.
// premul=1: record.y already holds w*dis[row]; premul=0: multiply dis[row].
__global__ void gather_kernel(const int* __restrict__ ptr, const uint2* __restrict__ erec,
                              const float* __restrict__ dis,
                              const unsigned short* __restrict__ src,
                              unsigned short* __restrict__ dst, int N, int premul) {
    int node = blockIdx.x * 4 + (threadIdx.x >> 6);
    int lane = threadIdx.x & 63;
    if (node >= N) return;
    int s = ptr[node];
    int d = ptr[node + 1] - s;
    const int h = lane >> 5;
    const int c2 = (lane & 31) * 2;
    float acc0 = 0.f, acc1 = 0.f;
    for (int base = 0; base < d; base += 64) {
        int n = min(64, d - base);
        int ex = 0;
        float w = 0.f;
        if (lane < n) {
            uint2 e = erec[s + base + lane];
            ex = (int)e.x;
            w = __uint_as_float(e.y);
            if (!premul) w *= dis[ex];
        }
        int n8 = (n + 7) & ~7;
        for (int j = 0; j < n8; j += 8) {
            int r0 = __shfl(ex, j + 0, 64), r1 = __shfl(ex, j + 1, 64);
            int r2 = __shfl(ex, j + 2, 64), r3 = __shfl(ex, j + 3, 64);
            int r4 = __shfl(ex, j + 4, 64), r5 = __shfl(ex, j + 5, 64);
            int r6 = __shfl(ex, j + 6, 64), r7 = __shfl(ex, j + 7, 64);
            float w0 = __shfl(w, j + 0, 64), w1 = __shfl(w, j + 1, 64);
            float w2 = __shfl(w, j + 2, 64), w3 = __shfl(w, j + 3, 64);
            float w4 = __shfl(w, j + 4, 64), w5 = __shfl(w, j + 5, 64);
            float w6 = __shfl(w, j + 6, 64), w7 = __shfl(w, j + 7, 64);
            int ra = h ? r1 : r0;  float wa = h ? w1 : w0;
            int rb = h ? r3 : r2;  float wb = h ? w3 : w2;
            int rc = h ? r5 : r4;  float wc = h ? w5 : w4;
            int rd = h ? r7 : r6;  float wd = h ? w7 : w6;
            unsigned va = *reinterpret_cast<const unsigned*>(src + (size_t)ra * 64 + c2);
            unsigned vb = *reinterpret_cast<const unsigned*>(src + (size_t)rb * 64 + c2);
            unsigned vc = *reinterpret_cast<const unsigned*>(src + (size_t)rc * 64 + c2);
            unsigned vd = *reinterpret_cast<const unsigned*>(src + (size_t)rd * 64 + c2);
            acc0 = fmaf(wa, bf2f((unsigned short)(va & 0xFFFFu)), acc0);
            acc1 = fmaf(wa, bf2f((unsigned short)(va >> 16)), acc1);
            acc0 = fmaf(wb, bf2f((unsigned short)(vb & 0xFFFFu)), acc0);
            acc1 = fmaf(wb, bf2f((unsigned short)(vb >> 16)), acc1);
            acc0 = fmaf(wc, bf2f((unsigned short)(vc & 0xFFFFu)), acc0);
            acc1 = fmaf(wc, bf2f((unsigned short)(vc >> 16)), acc1);
            acc0 = fmaf(wd, bf2f((unsigned short)(vd & 0xFFFFu)), acc0);
            acc1 = fmaf(wd, bf2f((unsigned short)(vd >> 16)), acc1);
        }
    }
    acc0 += __shfl_xor(acc0, 32, 64);
    acc1 += __shfl_xor(acc1, 32, 64);
    if (lane < 32) {
        float sc = -dis[node];
        unsigned o = (unsigned)f2bf(sc * acc0) | ((unsigned)f2bf(sc * acc1) << 16);
        *reinterpret_cast<unsigned*>(dst + (size_t)node * 64 + c2) = o;
    }
}

// ---- W pre-pack into fragment-native global images -----------------------
// imgW2[img][t(7)][ks(2)][lane(64)][j(8)]: lane l holds fragment shorts
// W[ks*32 + (l>>4)*8 + j][t*16 + (l&15)] for mfma_f32_16x16x32_bf16.
__global__ void prep_w_kernel(const float* __restrict__ W10, const float* __restrict__ W20,
                              const float* __restrict__ W21, const float* __restrict__ W30,
                              const float* __restrict__ W31, const float* __restrict__ W32,
                              unsigned short* __restrict__ imgW) {
    int i = blockIdx.x * 256 + threadIdx.x;
    if (i >= 6 * 7168) return;
    int img = i / 7168;
    int rem = i - img * 7168;
    int j = rem & 7;
    int l = (rem >> 3) & 63;
    int ks = (rem >> 9) & 1;
    int t = rem >> 10;            // 0..6
    const float* W;
    switch (img) {
        case 0: W = W10; break;
        case 1: W = W20; break;
        case 2: W = W21; break;
        case 3: W = W30; break;
        case 4: W = W31; break;
        default: W = W32; break;
    }
    int n = t * 16 + (l & 15);
    int k = ks * 32 + (l >> 4) * 8 + j;
    float v = (n < 100) ? W[k * 100 + n] : 0.f;
    imgW[i] = f2bf(v);
}

// ---- fused MFMA gemm: block = 64 rows x ALL 300 output cols --------------
// Operand-swapped MFMA: mfma(W_frag, X_frag) computes (X.W)^T so each lane
// holds 4 CONSECUTIVE output cols of one row -> float4 epilogue stores.
#define PRODUCT(AF, IMGOFF, SEGBASE)                                                   \
    do {                                                                               \
        _Pragma("unroll") for (int ks = 0; ks < 2; ++ks) {                             \
            _Pragma("unroll") for (int t = 0; t < 7; ++t) {                            \
                short8 bfr = *reinterpret_cast<const short8*>(                         \
                    imgW + (IMGOFF) + ((t * 2 + ks) << 9) + (l << 3));                 \
                acc[(SEGBASE) + t] = __builtin_amdgcn_mfma_f32_16x16x32_bf16(          \
                    bfr, AF[ks], acc[(SEGBASE) + t], 0, 0, 0);                         \
            }                                                                          \
        }                                                                              \
    } while (0)

__global__ __launch_bounds__(256) void gemm_fused_kernel(
        const unsigned short* __restrict__ xb, const unsigned short* __restrict__ tx1b,
        const unsigned short* __restrict__ p2b, const unsigned short* __restrict__ imgW,
        const float* __restrict__ b1, const float* __restrict__ b2,
        const float* __restrict__ b3, float* __restrict__ out, int N) {
    __shared__ unsigned short Ftx[64 * 64];
    __shared__ unsigned short Ft1[64 * 64];
    __shared__ unsigned short Ft2[64 * 64];
    const int row0 = blockIdx.x * 64;
    const int tid = threadIdx.x;
    const int wv = tid >> 6;
    const int l = tid & 63;
    const int m = l & 15;
    const int q = l >> 4;

    f32x4 acc[21];
#pragma unroll
    for (int t = 0; t < 21; ++t) acc[t] = (f32x4){0.f, 0.f, 0.f, 0.f};

    // stage all 3 A-tiles (swizzled LDS layout, conflict-free b128 reads)
#pragma unroll
    for (int it = 0; it < 2; ++it) {
        int i = tid + it * 256;
        int r = i >> 3, g = i & 7;
        int grow = row0 + r;
        ushort8 vx = {0, 0, 0, 0, 0, 0, 0, 0};
        ushort8 v1 = vx, v2 = vx;
        if (grow < N) {
            vx = *reinterpret_cast<const ushort8*>(xb + (size_t)grow * 64 + g * 8);
            v1 = *reinterpret_cast<const ushort8*>(tx1b + (size_t)grow * 64 + g * 8);
            ushort8 vp = *reinterpret_cast<const ushort8*>(p2b + (size_t)grow * 64 + g * 8);
#pragma unroll
            for (int jj = 0; jj < 8; ++jj)
                v2[jj] = f2bf(2.f * bf2f(vp[jj]) - bf2f(vx[jj]));  // tx2 = 2*p2 - x
        }
        int off = r * 64 + ((g ^ (r & 7)) << 3);
        *reinterpret_cast<ushort8*>(&Ftx[off]) = vx;
        *reinterpret_cast<ushort8*>(&Ft1[off]) = v1;
        *reinterpret_cast<ushort8*>(&Ft2[off]) = v2;
    }
    __syncthreads();

    const int arow = wv * 16 + m;
    short8 ax[2], a1[2], a2[2];
#pragma unroll
    for (int ks = 0; ks < 2; ++ks) {
        int o = arow * 64 + (((ks * 4 + q) ^ (arow & 7)) << 3);
        ax[ks] = *reinterpret_cast<const short8*>(&Ftx[o]);
        a1[ks] = *reinterpret_cast<const short8*>(&Ft1[o]);
        a2[ks] = *reinterpret_cast<const short8*>(&Ft2[o]);
    }

    PRODUCT(ax, 0, 0);          // seg0: T0 @ W10
    PRODUCT(ax, 7168, 7);       // seg1: T0 @ W20
    PRODUCT(a1, 14336, 7);      // seg1: T1 @ W21
    PRODUCT(ax, 21504, 14);     // seg2: T0 @ W30
    PRODUCT(a1, 28672, 14);     // seg2: T1 @ W31
    PRODUCT(a2, 35840, 14);     // seg2: T2 @ W32

    // epilogue: lane (wv,m) owns out row row0+wv*16+m; acc[seg*7+t][i] is
    // col seg*100 + t*16 + q*4 + i  -> contiguous float4 stores.
    const int grow = row0 + wv * 16 + m;
    if (grow < N) {
        float* orow = out + (size_t)grow * 300;
#pragma unroll
        for (int seg = 0; seg < 3; ++seg) {
            const float* bs = (seg == 0) ? b1 : (seg == 1) ? b2 : b3;
#pragma unroll
            for (int t = 0; t < 7; ++t) {
                int c0 = t * 16 + q * 4;
                if (c0 + 3 >= 100) continue;   // t=6: only q==0 (cols 96..99)
                float4 bv = *reinterpret_cast<const float4*>(bs + c0);
                f32x4 a = acc[seg * 7 + t];
                float4 o = make_float4(a[0] + bv.x, a[1] + bv.y, a[2] + bv.z, a[3] + bv.w);
                *reinterpret_cast<float4*>(orow + seg * 100 + c0) = o;
            }
        }
    }
}

extern "C" void kernel_launch(void* const* d_in, const int* in_sizes, int n_in,
                              void* d_out, int out_size, void* d_ws, size_t ws_size,
                              hipStream_t stream) {
    const float* x   = (const float*)d_in[0];
    const int*   ei  = (const int*)d_in[1];
    const float* ew  = (const float*)d_in[2];
    const float* W10 = (const float*)d_in[3];
    const float* b1  = (const float*)d_in[4];
    const float* W20 = (const float*)d_in[5];
    const float* W21 = (const float*)d_in[6];
    const float* b2  = (const float*)d_in[7];
    const float* W30 = (const float*)d_in[8];
    const float* W31 = (const float*)d_in[9];
    const float* W32 = (const float*)d_in[10];
    const float* b3  = (const float*)d_in[11];
    float* out = (float*)d_out;

    const int N = in_sizes[0] / 64;
    const int E = in_sizes[2];
    const int* row = ei;
    const int* col = ei + E;
    const int nb = (N + 255) / 256;
    const int eb = (E + 255) / 256;

    const int NSB = (N + 2047) >> 11;       // super-buckets (2048 nodes)
    const int nfb = NSB * 8;                // fine buckets (256 nodes)

    int total4 = N * 16;
    int pg = (N + 3) / 4;
    int ntile = (N + 63) / 64;

    // capacities with ~25% + constant slack
    long meanA = ((long)E * 2048 + N - 1) / N;
    int capA = (int)(meanA + meanA / 4 + 1024);
    long meanB = ((long)E * 256 + N - 1) / N;
    int capB = (int)(meanB + meanB / 4 + 512);

    char* base = (char*)d_ws;
    size_t off = 0;
    auto alloc = [&](size_t bytes) { size_t o = off; off = (off + bytes + 15) & ~(size_t)15; return o; };

    // ---- fixed allocations (shared by both paths) ----
    float* dis           = (float*)(base + alloc((size_t)4 * N));
    int*   rowptr        = (int*)(base + alloc((size_t)4 * (N + 1)));
    int*   colAcur       = (int*)(base + alloc((size_t)4 * 640));   // 64+64+512 cursors
    int*   rowAcur       = colAcur + 64;
    int*   colBcur       = colAcur + 128;
    int*   colbase       = (int*)(base + alloc((size_t)4 * 512));
    unsigned short* xb   = (unsigned short*)(base + alloc((size_t)128 * N));
    unsigned short* tx1b = (unsigned short*)(base + alloc((size_t)128 * N));
    unsigned short* p2b  = (unsigned short*)(base + alloc((size_t)128 * N));
    unsigned short* imgW = (unsigned short*)(base + alloc((size_t)2 * 6 * 7168));
    uint2* erec          = (uint2*)(base + alloc((size_t)8 * E));
    size_t mainfix = off;
    uint2* colA          = (uint2*)(base + alloc((size_t)8 * NSB * capA));
    uint2* rowA          = (uint2*)(base + alloc((size_t)8 * NSB * capA));
    uint2* colB          = (uint2*)(base + alloc((size_t)8 * nfb * capB));
    float* partial       = (float*)(base + alloc((size_t)4 * NSB * NSPLIT_ROW * 2048));
    size_t mainneed = off;

    bool mainok = (N <= 131072) && (NSB <= NSBMAX) && (nfb <= 512) && (mainneed <= ws_size);

    if (mainok) {
        const int PBLK = 1024;
        int chunkA = (E + PBLK - 1) / PBLK;

        hipMemsetAsync(colAcur, 0, (size_t)4 * 640, stream);
        partA_kernel<<<PBLK, 512, 0, stream>>>(row, col, ew, colAcur, rowAcur,
                                               colA, rowA, E, NSB, chunkA, capA);
        partB_kernel<<<NSB * NSPLIT, 512, 0, stream>>>(colAcur, colA, colBcur, colB,
                                                       capA, capB);
        fine_rowp_kernel<<<NSB * NSPLIT_ROW, 512, 0, stream>>>(rowAcur, rowA, partial, capA);
        cvt_dis_kernel<<<(total4 + 255) / 256, 256, 0, stream>>>(x, xb, partial, dis,
                                                                 N, total4, 2);
        colbase_scan_kernel<<<1, 512, 0, stream>>>(colBcur, colbase, rowptr, N, nfb, capB);
        fine_col_kernel<<<nfb, 256, 0, stream>>>(colBcur, colbase, colB, dis,
                                                 erec, rowptr, N, capB);
        prep_w_kernel<<<(6 * 7168 + 255) / 256, 256, 0, stream>>>(W10, W20, W21, W30, W31, W32, imgW);

        gather_kernel<<<pg, 256, 0, stream>>>(rowptr, erec, dis, xb, tx1b, N, 1);
        gather_kernel<<<pg, 256, 0, stream>>>(rowptr, erec, dis, tx1b, p2b, N, 1);
        gemm_fused_kernel<<<ntile, 256, 0, stream>>>(xb, tx1b, p2b, imgW, b1, b2, b3, out, N);
    } else {
        // ---- compact-CSR fallback (device-scope atomics) ----
        off = mainfix;
        float* deg    = (float*)(base + alloc((size_t)4 * N));
        int*   cursor = (int*)(base + alloc((size_t)4 * N));
        int*   bsum   = (int*)(base + alloc((size_t)4 * nb));
        int*   bpre   = (int*)(base + alloc((size_t)4 * nb));

        hipMemsetAsync(deg, 0, (size_t)4 * N, stream);
        hipMemsetAsync(cursor, 0, (size_t)4 * N, stream);
        deg_count_kernel<<<eb, 256, 0, stream>>>(row, col, ew, deg, cursor, E);
        scan1_kernel<<<nb, 256, 0, stream>>>(cursor, rowptr, bsum, N);
        scan2_kernel<<<1, 512, 0, stream>>>(bsum, bpre, nb);
        scan3_kernel<<<nb, 256, 0, stream>>>(rowptr, cursor, bpre, N, E);
        scatter_compact_kernel<<<eb, 256, 0, stream>>>(row, col, ew, cursor, erec, E);
        cvt_dis_kernel<<<(total4 + 255) / 256, 256, 0, stream>>>(x, xb, deg, dis, N, total4, 1);
        prep_w_kernel<<<(6 * 7168 + 255) / 256, 256, 0, stream>>>(W10, W20, W21, W30, W31, W32, imgW);

        gather_kernel<<<pg, 256, 0, stream>>>(rowptr, erec, dis, xb, tx1b, N, 0);
        gather_kernel<<<pg, 256, 0, stream>>>(rowptr, erec, dis, tx1b, p2b, N, 0);
        gemm_fused_kernel<<<ntile, 256, 0, stream>>>(xb, tx1b, p2b, imgW, b1, b2, b3, out, N);
    }
}